// Round 10
// baseline (95.129 us; speedup 1.0000x reference)
//
#include <hip/hip_runtime.h>

// Problem constants
#define K_CODES 512
#define DIM 80
#define SEQ 4096
#define NVEC 131072
#define NELEM ((size_t)NVEC * DIM)
#define VPB 128                      // vectors per block: 4 waves x 32 vectors
#define NTILES (K_CODES / 16)        // 32 code tiles
#define TILE_BYTES 6144              // 384 short8 per tile

typedef short short8 __attribute__((ext_vector_type(8)));
typedef float f32x4 __attribute__((ext_vector_type(4)));

// ws layout: ghist[512] @0 | gsq @2048 | wsq[512] @4096 | wfrag @8192 (196608 B) | bk @204800
#define WS_GSQ   2048
#define WS_WSQ   4096
#define WS_WFRAG 8192
#define WS_BK    (8192 + 196608)

__device__ __forceinline__ unsigned short f2bf(float f) {
    union { float f; unsigned int u; } c; c.f = f;
    unsigned int r = c.u + 0x7FFFu + ((c.u >> 16) & 1u);   // RNE
    return (unsigned short)(r >> 16);
}
__device__ __forceinline__ float bf2f(unsigned short h) {
    union { float f; unsigned int u; } c; c.u = ((unsigned int)h) << 16;
    return c.f;
}

__device__ __forceinline__ void gload_lds16(const void* g, void* l) {
    __builtin_amdgcn_global_load_lds(
        (const __attribute__((address_space(1))) void*)g,
        (__attribute__((address_space(3))) void*)l, 16, 0, 0);
}

// Fused setup: wfrag (fragment-ordered split codebook) + wsq (row norms).
// wfrag: [tile 0..31][g 0..5][lane 0..63] short8; g<3: hi,ks=g; g>=3: lo,ks=g-3;
//        lane=(cg<<4)|cl; value = w{hi,lo}[code=tile*16+cl][c=ks*32+cg*8 ..+8)
__global__ void vq_setup(const float* __restrict__ weight,
                         short8* __restrict__ wf, float* __restrict__ wsq)
{
    int idx = blockIdx.x * 256 + threadIdx.x;   // 48 blocks -> 12288
    if (blockIdx.x < 2) {
        int k = blockIdx.x * 256 + threadIdx.x;
        const float* w = weight + (size_t)k * DIM;
        float s = 0.f;
#pragma unroll
        for (int c = 0; c < DIM; ++c) s = fmaf(w[c], w[c], s);
        wsq[k] = s;
    }
    int t   = idx / 384;
    int rem = idx - t * 384;
    int g   = rem >> 6, l = rem & 63;
    int cl  = l & 15, cg = l >> 4;
    int ks  = g % 3, h = g / 3;
    int code = t * 16 + cl;
    int c0 = ks * 32 + cg * 8;
    short8 v;
#pragma unroll
    for (int j = 0; j < 8; ++j) {
        int c = c0 + j;
        unsigned short r = 0;
        if (c < DIM) {
            float f = weight[(size_t)code * DIM + c];
            unsigned short hb = f2bf(f);
            r = h ? f2bf(f - bf2f(hb)) : hb;
        }
        v[j] = (short)r;
    }
    wf[idx] = v;
}

// Distance GEMM + argmin. 3-buffer LDS pipeline, 2 tiles prefetched ahead,
// counted s_waitcnt vmcnt(2) + raw s_barrier (never drain to 0 in the loop).
// Staging: waves 0..2 each stage 1024B x2 per tile (wave-uniform LDS dest).
// Per tile: 6 ds_read_b128 + 18 MFMA (hh+hl+lh; ll dropped, ~1e-4 error).
__global__ __launch_bounds__(256, 3) void vq_argmin(
    const float* __restrict__ x, const short8* __restrict__ wf,
    const float* __restrict__ wsq,
    int* __restrict__ bk, int* __restrict__ ghist)
{
    __shared__ short8 bbuf[3][384];   // 3 x 6 KB, fragment-ordered B tiles
    __shared__ int lhist[K_CODES];

    const int tid = threadIdx.x;
    for (int i = tid; i < K_CODES; i += 256) lhist[i] = 0;

    const int v0 = blockIdx.x * VPB;
    const int b  = v0 >> 12;
    const int l0 = v0 & 4095;
    const float* xbase = x + (size_t)b * DIM * SEQ + l0;

    const int lane = tid & 63, wid = tid >> 6;
    const int cg = lane >> 4;          // k-group 0..3
    const int cl = lane & 15;          // A row / B col
    const int ar0 = wid * 32 + cl;     // set-0 local vector
    const int ar1 = ar0 + 16;          // set-1
    const bool stager = (wid < 3);     // waves 0..2 stage 2048 B each per tile

    // ---- prologue: stage tiles 0 and 1 (2 gload_lds16 per staging wave each) ----
    if (stager) {
        const char* s0 = (const char*)wf + wid * 2048 + lane * 16;
        char* d0 = (char*)&bbuf[0][0] + wid * 2048 + lane * 16;
        gload_lds16(s0, d0);
        gload_lds16(s0 + 1024, d0 + 1024);
        const char* s1 = s0 + TILE_BYTES;
        char* d1 = (char*)&bbuf[1][0] + wid * 2048 + lane * 16;
        gload_lds16(s1, d1);
        gload_lds16(s1 + 1024, d1 + 1024);
    }

    // ---- A fragments (2 sets, hi/lo), direct from global ----
    short8 ahi0[3], alo0[3], ahi1[3], alo1[3];
#pragma unroll
    for (int ks = 0; ks < 3; ++ks) {
#pragma unroll
        for (int j = 0; j < 8; ++j) {
            int c = ks * 32 + cg * 8 + j;
            unsigned short h0 = 0, p0 = 0, h1 = 0, p1 = 0;
            if (c < DIM) {
                float f0 = xbase[(size_t)c * SEQ + ar0];
                float f1 = xbase[(size_t)c * SEQ + ar1];
                h0 = f2bf(f0); p0 = f2bf(f0 - bf2f(h0));
                h1 = f2bf(f1); p1 = f2bf(f1 - bf2f(h1));
            }
            ahi0[ks][j] = (short)h0; alo0[ks][j] = (short)p0;
            ahi1[ks][j] = (short)h1; alo1[ks][j] = (short)p1;
        }
    }

    float bestd[2][4];
    int   bestk[2][4];
#pragma unroll
    for (int s = 0; s < 2; ++s)
#pragma unroll
        for (int r = 0; r < 4; ++r) { bestd[s][r] = 3.4028235e38f; bestk[s][r] = 0; }

    for (int t = 0; t < NTILES; ++t) {
        // wait: my tile-t staging done (leave tile-(t+1)'s 2 ops in flight)
        if (stager) asm volatile("s_waitcnt vmcnt(2)" ::: "memory");
        __builtin_amdgcn_sched_barrier(0);
        __builtin_amdgcn_s_barrier();   // all waves: tile t staged; tile t-1 reads done
        __builtin_amdgcn_sched_barrier(0);

        // prefetch tile t+2 into buffer (t+2)%3 (its old content t-1: reads done)
        if (t + 2 < NTILES && stager) {
            const char* src = (const char*)wf + (size_t)(t + 2) * TILE_BYTES + wid * 2048 + lane * 16;
            char* dst = (char*)&bbuf[(t + 2) % 3][0] + wid * 2048 + lane * 16;
            gload_lds16(src, dst);
            gload_lds16(src + 1024, dst + 1024);
        }

        const short8* bb = bbuf[t % 3];
        short8 bh0 = bb[lane];
        short8 bh1 = bb[64 + lane];
        short8 bh2 = bb[128 + lane];
        short8 bl0 = bb[192 + lane];
        short8 bl1 = bb[256 + lane];
        short8 bl2 = bb[320 + lane];

        f32x4 a00 = {0.f,0.f,0.f,0.f}, a01 = {0.f,0.f,0.f,0.f}, a02 = {0.f,0.f,0.f,0.f};
        f32x4 a10 = {0.f,0.f,0.f,0.f}, a11 = {0.f,0.f,0.f,0.f}, a12 = {0.f,0.f,0.f,0.f};
        __builtin_amdgcn_s_setprio(1);
        // set 0: hh, hl, lh (same accumulation structure as verified R6-R9)
        a00 = __builtin_amdgcn_mfma_f32_16x16x32_bf16(ahi0[0], bh0, a00, 0, 0, 0);
        a01 = __builtin_amdgcn_mfma_f32_16x16x32_bf16(ahi0[1], bh1, a01, 0, 0, 0);
        a02 = __builtin_amdgcn_mfma_f32_16x16x32_bf16(ahi0[2], bh2, a02, 0, 0, 0);
        a00 = __builtin_amdgcn_mfma_f32_16x16x32_bf16(ahi0[0], bl0, a00, 0, 0, 0);
        a01 = __builtin_amdgcn_mfma_f32_16x16x32_bf16(ahi0[1], bl1, a01, 0, 0, 0);
        a02 = __builtin_amdgcn_mfma_f32_16x16x32_bf16(ahi0[2], bl2, a02, 0, 0, 0);
        a00 = __builtin_amdgcn_mfma_f32_16x16x32_bf16(alo0[0], bh0, a00, 0, 0, 0);
        a01 = __builtin_amdgcn_mfma_f32_16x16x32_bf16(alo0[1], bh1, a01, 0, 0, 0);
        a02 = __builtin_amdgcn_mfma_f32_16x16x32_bf16(alo0[2], bh2, a02, 0, 0, 0);
        // set 1
        a10 = __builtin_amdgcn_mfma_f32_16x16x32_bf16(ahi1[0], bh0, a10, 0, 0, 0);
        a11 = __builtin_amdgcn_mfma_f32_16x16x32_bf16(ahi1[1], bh1, a11, 0, 0, 0);
        a12 = __builtin_amdgcn_mfma_f32_16x16x32_bf16(ahi1[2], bh2, a12, 0, 0, 0);
        a10 = __builtin_amdgcn_mfma_f32_16x16x32_bf16(ahi1[0], bl0, a10, 0, 0, 0);
        a11 = __builtin_amdgcn_mfma_f32_16x16x32_bf16(ahi1[1], bl1, a11, 0, 0, 0);
        a12 = __builtin_amdgcn_mfma_f32_16x16x32_bf16(ahi1[2], bl2, a12, 0, 0, 0);
        a10 = __builtin_amdgcn_mfma_f32_16x16x32_bf16(alo1[0], bh0, a10, 0, 0, 0);
        a11 = __builtin_amdgcn_mfma_f32_16x16x32_bf16(alo1[1], bh1, a11, 0, 0, 0);
        a12 = __builtin_amdgcn_mfma_f32_16x16x32_bf16(alo1[2], bh2, a12, 0, 0, 0);
        __builtin_amdgcn_s_setprio(0);

        const int code = t * 16 + cl;
        float wv = wsq[code];
#pragma unroll
        for (int r = 0; r < 4; ++r) {
            float d0 = a00[r] + a01[r] + a02[r];
            float q0 = fmaf(-2.f, d0, wv);
            if (q0 < bestd[0][r]) { bestd[0][r] = q0; bestk[0][r] = code; }
            float d1 = a10[r] + a11[r] + a12[r];
            float q1 = fmaf(-2.f, d1, wv);
            if (q1 < bestd[1][r]) { bestd[1][r] = q1; bestk[1][r] = code; }
        }
    }

    // ---- cross-lane argmin over 16-code column groups (lexicographic) ----
#pragma unroll
    for (int s = 0; s < 2; ++s) {
#pragma unroll
        for (int r = 0; r < 4; ++r) {
            float d = bestd[s][r]; int k = bestk[s][r];
#pragma unroll
            for (int off = 1; off < 16; off <<= 1) {
                float od = __shfl_xor(d, off, 64);
                int   ok = __shfl_xor(k, off, 64);
                if (od < d || (od == d && ok < k)) { d = od; k = ok; }
            }
            if (cl == 0) {
                int vloc = wid * 32 + s * 16 + cg * 4 + r;   // D row=(lane>>4)*4+reg
                bk[v0 + vloc] = k;
                atomicAdd(&lhist[k], 1);
            }
        }
    }
    __syncthreads();
    for (int i = tid; i < K_CODES; i += 256) {
        int cnt = lhist[i];
        if (cnt) atomicAdd(&ghist[i], cnt);
    }
}

// Memory-bound epilogue: thread = vector. Row-gather codebook (float4,
// exact fp32), coalesced x reads / out writes, loss accumulation.
__global__ __launch_bounds__(256) void vq_epilogue(
    const float* __restrict__ x, const float* __restrict__ weight,
    const int* __restrict__ bk, float* __restrict__ out,
    float* __restrict__ gsq)
{
    __shared__ float lsum[4];
    const int tid = threadIdx.x;
    const int v = blockIdx.x * 256 + tid;
    const int b = v >> 12;
    const int l = v & 4095;
    const float* xp = x + (size_t)b * DIM * SEQ + l;
    const float* wr = weight + (size_t)bk[v] * DIM;
    float* op = out + 1 + (size_t)b * DIM * SEQ + l;

    float sq = 0.f;
#pragma unroll
    for (int c = 0; c < DIM; c += 4) {
        float4 wv = *(const float4*)(wr + c);
        float x0 = xp[(size_t)(c + 0) * SEQ];
        float x1 = xp[(size_t)(c + 1) * SEQ];
        float x2 = xp[(size_t)(c + 2) * SEQ];
        float x3 = xp[(size_t)(c + 3) * SEQ];
        float e0 = wv.x - x0, e1 = wv.y - x1, e2 = wv.z - x2, e3 = wv.w - x3;
        sq = fmaf(e0, e0, sq);
        sq = fmaf(e1, e1, sq);
        sq = fmaf(e2, e2, sq);
        sq = fmaf(e3, e3, sq);
        op[(size_t)(c + 0) * SEQ] = wv.x;
        op[(size_t)(c + 1) * SEQ] = wv.y;
        op[(size_t)(c + 2) * SEQ] = wv.z;
        op[(size_t)(c + 3) * SEQ] = wv.w;
    }

#pragma unroll
    for (int off = 32; off; off >>= 1) sq += __shfl_down(sq, off, 64);
    if ((tid & 63) == 0) lsum[tid >> 6] = sq;
    __syncthreads();
    if (tid == 0) {
        float s = lsum[0] + lsum[1] + lsum[2] + lsum[3];
        atomicAdd(gsq, s);
    }
}

__global__ void vq_finalize(const int* __restrict__ hist,
                            const float* __restrict__ gsq,
                            float* __restrict__ out, int out_last)
{
    __shared__ float part[8];
    int t = threadIdx.x;  // 512 threads
    float p = (float)hist[t] * (1.0f / (float)NVEC);
    float term = p * logf(p + 1e-10f);
#pragma unroll
    for (int off = 32; off; off >>= 1) term += __shfl_down(term, off, 64);
    if ((t & 63) == 0) part[t >> 6] = term;
    __syncthreads();
    if (t == 0) {
        float s = 0.f;
#pragma unroll
        for (int i = 0; i < 8; ++i) s += part[i];
        out[out_last] = expf(-s);
        out[0] = 1.25f * gsq[0] / (float)NELEM;
    }
}

extern "C" void kernel_launch(void* const* d_in, const int* in_sizes, int n_in,
                              void* d_out, int out_size, void* d_ws, size_t ws_size,
                              hipStream_t stream) {
    const float* x = (const float*)d_in[0];
    const float* weight = (const float*)d_in[1];
    float* out = (float*)d_out;

    int* ghist = (int*)d_ws;
    float* gsq = (float*)((char*)d_ws + WS_GSQ);
    float* wsq = (float*)((char*)d_ws + WS_WSQ);
    short8* wf = (short8*)((char*)d_ws + WS_WFRAG);
    int* bk = (int*)((char*)d_ws + WS_BK);

    hipMemsetAsync(d_ws, 0, 2052, stream);

    vq_setup<<<48, 256, 0, stream>>>(weight, wf, wsq);
    vq_argmin<<<NVEC / VPB, 256, 0, stream>>>(x, wf, wsq, bk, ghist);
    vq_epilogue<<<NVEC / 256, 256, 0, stream>>>(x, weight, bk, out, gsq);
    vq_finalize<<<1, K_CODES, 0, stream>>>(ghist, gsq, out, out_size - 1);
}

// Round 11
// 93.401 us; speedup vs baseline: 1.0185x; 1.0185x over previous
//
#include <hip/hip_runtime.h>

// Problem constants
#define K_CODES 512
#define DIM 80
#define SEQ 4096
#define NVEC 131072
#define NELEM ((size_t)NVEC * DIM)
#define VPB 256                      // vectors per block: 4 waves x 4 sets x 16
#define NSET 4                       // A-sets (16 vectors each) per wave
#define NTILES (K_CODES / 16)        // 32 code tiles
#define TILE_BYTES 6144              // 384 short8 per tile

typedef short short8 __attribute__((ext_vector_type(8)));
typedef float f32x4 __attribute__((ext_vector_type(4)));

// ws layout: ghist[512] @0 | gsq @2048 | wsq[512] @4096 | wfrag @8192 (196608 B) | bk @204800
#define WS_GSQ   2048
#define WS_WSQ   4096
#define WS_WFRAG 8192
#define WS_BK    (8192 + 196608)

__device__ __forceinline__ unsigned short f2bf(float f) {
    union { float f; unsigned int u; } c; c.f = f;
    unsigned int r = c.u + 0x7FFFu + ((c.u >> 16) & 1u);   // RNE
    return (unsigned short)(r >> 16);
}
__device__ __forceinline__ float bf2f(unsigned short h) {
    union { float f; unsigned int u; } c; c.u = ((unsigned int)h) << 16;
    return c.f;
}

__device__ __forceinline__ void gload_lds16(const void* g, void* l) {
    __builtin_amdgcn_global_load_lds(
        (const __attribute__((address_space(1))) void*)g,
        (__attribute__((address_space(3))) void*)l, 16, 0, 0);
}

// Fused setup: wfrag (fragment-ordered split codebook) + wsq (row norms).
// wfrag: [tile 0..31][g 0..5][lane 0..63] short8; g<3: hi,ks=g; g>=3: lo,ks=g-3;
//        lane=(cg<<4)|cl; value = w{hi,lo}[code=tile*16+cl][c=ks*32+cg*8 ..+8)
__global__ void vq_setup(const float* __restrict__ weight,
                         short8* __restrict__ wf, float* __restrict__ wsq)
{
    int idx = blockIdx.x * 256 + threadIdx.x;   // 48 blocks -> 12288
    if (blockIdx.x < 2) {
        int k = blockIdx.x * 256 + threadIdx.x;
        const float* w = weight + (size_t)k * DIM;
        float s = 0.f;
#pragma unroll
        for (int c = 0; c < DIM; ++c) s = fmaf(w[c], w[c], s);
        wsq[k] = s;
    }
    int t   = idx / 384;
    int rem = idx - t * 384;
    int g   = rem >> 6, l = rem & 63;
    int cl  = l & 15, cg = l >> 4;
    int ks  = g % 3, h = g / 3;
    int code = t * 16 + cl;
    int c0 = ks * 32 + cg * 8;
    short8 v;
#pragma unroll
    for (int j = 0; j < 8; ++j) {
        int c = c0 + j;
        unsigned short r = 0;
        if (c < DIM) {
            float f = weight[(size_t)code * DIM + c];
            unsigned short hb = f2bf(f);
            r = h ? f2bf(f - bf2f(hb)) : hb;
        }
        v[j] = (short)r;
    }
    wf[idx] = v;
}

// Distance GEMM + argmin. 4 A-sets/wave (64 vec), 36 MFMA per tile phase
// (4 independent 9-deep C-chained accumulators). 3-buffer LDS pipeline,
// 2 tiles ahead, counted vmcnt(2) + raw s_barrier. wsq served from LDS so
// staging loads are the ONLY in-loop VMEM (vmcnt semantics preserved).
__global__ __launch_bounds__(256, 2) void vq_argmin(
    const float* __restrict__ x, const short8* __restrict__ wf,
    const float* __restrict__ wsq,
    int* __restrict__ bk, int* __restrict__ ghist)
{
    __shared__ short8 bbuf[3][384];   // 3 x 6 KB, fragment-ordered B tiles
    __shared__ float wsq_lds[K_CODES];
    __shared__ int lhist[K_CODES];

    const int tid = threadIdx.x;
    for (int i = tid; i < K_CODES; i += 256) lhist[i] = 0;

    const int v0 = blockIdx.x * VPB;
    const int b  = v0 >> 12;
    const int l0 = v0 & 4095;
    const float* xbase = x + (size_t)b * DIM * SEQ + l0;

    const int lane = tid & 63, wid = tid >> 6;
    const int cg = lane >> 4;          // k-group 0..3
    const int cl = lane & 15;          // A row / B col
    const bool stager = (wid < 3);     // waves 0..2 stage 2048 B each per tile

    // ---- prologue staging: tiles 0,1 (waves 0-2); wsq -> LDS (wave 3) ----
    if (stager) {
        const char* s0 = (const char*)wf + wid * 2048 + lane * 16;
        char* d0 = (char*)&bbuf[0][0] + wid * 2048 + lane * 16;
        gload_lds16(s0, d0);
        gload_lds16(s0 + 1024, d0 + 1024);
        const char* s1 = s0 + TILE_BYTES;
        char* d1 = (char*)&bbuf[1][0] + wid * 2048 + lane * 16;
        gload_lds16(s1, d1);
        gload_lds16(s1 + 1024, d1 + 1024);
    } else {
        gload_lds16((const char*)wsq + lane * 16, (char*)wsq_lds + lane * 16);
        gload_lds16((const char*)wsq + 1024 + lane * 16, (char*)wsq_lds + 1024 + lane * 16);
    }

    // ---- A fragments: 4 sets x (hi,lo) x 3 k-steps, direct from global ----
    short8 ahi[NSET][3], alo[NSET][3];
#pragma unroll
    for (int s = 0; s < NSET; ++s) {
        const int ar = wid * 64 + s * 16 + cl;
#pragma unroll
        for (int ks = 0; ks < 3; ++ks) {
#pragma unroll
            for (int j = 0; j < 8; ++j) {
                int c = ks * 32 + cg * 8 + j;
                unsigned short hb = 0, lb = 0;
                if (c < DIM) {
                    float f = xbase[(size_t)c * SEQ + ar];
                    hb = f2bf(f);
                    lb = f2bf(f - bf2f(hb));
                }
                ahi[s][ks][j] = (short)hb;
                alo[s][ks][j] = (short)lb;
            }
        }
    }

    // wave 3: drain wsq staging before first barrier (it never waits vmcnt later)
    if (!stager) asm volatile("s_waitcnt vmcnt(0)" ::: "memory");

    float bestd[NSET][4];
    int   bestk[NSET][4];
#pragma unroll
    for (int s = 0; s < NSET; ++s)
#pragma unroll
        for (int r = 0; r < 4; ++r) { bestd[s][r] = 3.4028235e38f; bestk[s][r] = 0; }

    for (int t = 0; t < NTILES; ++t) {
        // wait: my tile-t staging done (leave tile-(t+1)'s 2 ops in flight)
        if (stager) asm volatile("s_waitcnt vmcnt(2)" ::: "memory");
        __builtin_amdgcn_sched_barrier(0);
        __builtin_amdgcn_s_barrier();   // tile t staged; tile t-1 reads done
        __builtin_amdgcn_sched_barrier(0);

        // prefetch tile t+2 into buffer (t+2)%3
        if (t + 2 < NTILES && stager) {
            const char* src = (const char*)wf + (size_t)(t + 2) * TILE_BYTES + wid * 2048 + lane * 16;
            char* dst = (char*)&bbuf[(t + 2) % 3][0] + wid * 2048 + lane * 16;
            gload_lds16(src, dst);
            gload_lds16(src + 1024, dst + 1024);
        }

        const short8* bb = bbuf[t % 3];
        short8 bh0 = bb[lane];
        short8 bh1 = bb[64 + lane];
        short8 bh2 = bb[128 + lane];
        short8 bl0 = bb[192 + lane];
        short8 bl1 = bb[256 + lane];
        short8 bl2 = bb[320 + lane];
        float wsqv = wsq_lds[t * 16 + cl];

        f32x4 acc0 = {0.f,0.f,0.f,0.f}, acc1 = {0.f,0.f,0.f,0.f};
        f32x4 acc2 = {0.f,0.f,0.f,0.f}, acc3 = {0.f,0.f,0.f,0.f};
        __builtin_amdgcn_s_setprio(1);
#define MF4(A, KS, B) \
        acc0 = __builtin_amdgcn_mfma_f32_16x16x32_bf16(A[0][KS], B, acc0, 0, 0, 0); \
        acc1 = __builtin_amdgcn_mfma_f32_16x16x32_bf16(A[1][KS], B, acc1, 0, 0, 0); \
        acc2 = __builtin_amdgcn_mfma_f32_16x16x32_bf16(A[2][KS], B, acc2, 0, 0, 0); \
        acc3 = __builtin_amdgcn_mfma_f32_16x16x32_bf16(A[3][KS], B, acc3, 0, 0, 0);
        // per set: 9-deep chain  hh0,hh1,hh2, hl0,hl1,hl2, lh0,lh1,lh2
        MF4(ahi, 0, bh0)
        MF4(ahi, 1, bh1)
        MF4(ahi, 2, bh2)
        MF4(ahi, 0, bl0)
        MF4(ahi, 1, bl1)
        MF4(ahi, 2, bl2)
        MF4(alo, 0, bh0)
        MF4(alo, 1, bh1)
        MF4(alo, 2, bh2)
#undef MF4
        __builtin_amdgcn_s_setprio(0);

        const int code = t * 16 + cl;
#pragma unroll
        for (int r = 0; r < 4; ++r) {
            float q0 = fmaf(-2.f, acc0[r], wsqv);
            if (q0 < bestd[0][r]) { bestd[0][r] = q0; bestk[0][r] = code; }
            float q1 = fmaf(-2.f, acc1[r], wsqv);
            if (q1 < bestd[1][r]) { bestd[1][r] = q1; bestk[1][r] = code; }
            float q2 = fmaf(-2.f, acc2[r], wsqv);
            if (q2 < bestd[2][r]) { bestd[2][r] = q2; bestk[2][r] = code; }
            float q3 = fmaf(-2.f, acc3[r], wsqv);
            if (q3 < bestd[3][r]) { bestd[3][r] = q3; bestk[3][r] = code; }
        }
    }

    // ---- cross-lane argmin over 16-code column groups (lexicographic) ----
#pragma unroll
    for (int s = 0; s < NSET; ++s) {
#pragma unroll
        for (int r = 0; r < 4; ++r) {
            float d = bestd[s][r]; int k = bestk[s][r];
#pragma unroll
            for (int off = 1; off < 16; off <<= 1) {
                float od = __shfl_xor(d, off, 64);
                int   ok = __shfl_xor(k, off, 64);
                if (od < d || (od == d && ok < k)) { d = od; k = ok; }
            }
            if (cl == 0) {
                int vloc = wid * 64 + s * 16 + cg * 4 + r;   // D row=(lane>>4)*4+reg
                bk[v0 + vloc] = k;
                atomicAdd(&lhist[k], 1);
            }
        }
    }
    __syncthreads();
    for (int i = tid; i < K_CODES; i += 256) {
        int cnt = lhist[i];
        if (cnt) atomicAdd(&ghist[i], cnt);
    }
}

// Memory-bound epilogue: thread = vector. Row-gather codebook (float4,
// exact fp32), coalesced x reads / out writes, loss accumulation.
__global__ __launch_bounds__(256) void vq_epilogue(
    const float* __restrict__ x, const float* __restrict__ weight,
    const int* __restrict__ bk, float* __restrict__ out,
    float* __restrict__ gsq)
{
    __shared__ float lsum[4];
    const int tid = threadIdx.x;
    const int v = blockIdx.x * 256 + tid;
    const int b = v >> 12;
    const int l = v & 4095;
    const float* xp = x + (size_t)b * DIM * SEQ + l;
    const float* wr = weight + (size_t)bk[v] * DIM;
    float* op = out + 1 + (size_t)b * DIM * SEQ + l;

    float sq = 0.f;
#pragma unroll
    for (int c = 0; c < DIM; c += 4) {
        float4 wv = *(const float4*)(wr + c);
        float x0 = xp[(size_t)(c + 0) * SEQ];
        float x1 = xp[(size_t)(c + 1) * SEQ];
        float x2 = xp[(size_t)(c + 2) * SEQ];
        float x3 = xp[(size_t)(c + 3) * SEQ];
        float e0 = wv.x - x0, e1 = wv.y - x1, e2 = wv.z - x2, e3 = wv.w - x3;
        sq = fmaf(e0, e0, sq);
        sq = fmaf(e1, e1, sq);
        sq = fmaf(e2, e2, sq);
        sq = fmaf(e3, e3, sq);
        op[(size_t)(c + 0) * SEQ] = wv.x;
        op[(size_t)(c + 1) * SEQ] = wv.y;
        op[(size_t)(c + 2) * SEQ] = wv.z;
        op[(size_t)(c + 3) * SEQ] = wv.w;
    }

#pragma unroll
    for (int off = 32; off; off >>= 1) sq += __shfl_down(sq, off, 64);
    if ((tid & 63) == 0) lsum[tid >> 6] = sq;
    __syncthreads();
    if (tid == 0) {
        float s = lsum[0] + lsum[1] + lsum[2] + lsum[3];
        atomicAdd(gsq, s);
    }
}

__global__ void vq_finalize(const int* __restrict__ hist,
                            const float* __restrict__ gsq,
                            float* __restrict__ out, int out_last)
{
    __shared__ float part[8];
    int t = threadIdx.x;  // 512 threads
    float p = (float)hist[t] * (1.0f / (float)NVEC);
    float term = p * logf(p + 1e-10f);
#pragma unroll
    for (int off = 32; off; off >>= 1) term += __shfl_down(term, off, 64);
    if ((t & 63) == 0) part[t >> 6] = term;
    __syncthreads();
    if (t == 0) {
        float s = 0.f;
#pragma unroll
        for (int i = 0; i < 8; ++i) s += part[i];
        out[out_last] = expf(-s);
        out[0] = 1.25f * gsq[0] / (float)NELEM;
    }
}

extern "C" void kernel_launch(void* const* d_in, const int* in_sizes, int n_in,
                              void* d_out, int out_size, void* d_ws, size_t ws_size,
                              hipStream_t stream) {
    const float* x = (const float*)d_in[0];
    const float* weight = (const float*)d_in[1];
    float* out = (float*)d_out;

    int* ghist = (int*)d_ws;
    float* gsq = (float*)((char*)d_ws + WS_GSQ);
    float* wsq = (float*)((char*)d_ws + WS_WSQ);
    short8* wf = (short8*)((char*)d_ws + WS_WFRAG);
    int* bk = (int*)((char*)d_ws + WS_BK);

    hipMemsetAsync(d_ws, 0, 2052, stream);

    vq_setup<<<48, 256, 0, stream>>>(weight, wf, wsq);
    vq_argmin<<<NVEC / VPB, 256, 0, stream>>>(x, wf, wsq, bk, ghist);
    vq_epilogue<<<NVEC / 256, 256, 0, stream>>>(x, weight, bk, out, gsq);
    vq_finalize<<<1, K_CODES, 0, stream>>>(ghist, gsq, out, out_size - 1);
}